// Round 1
// 138.478 us; speedup vs baseline: 1.0103x; 1.0103x over previous
//
#include <hip/hip_runtime.h>
#include <hip/hip_bf16.h>
#include <stdint.h>
#include <stddef.h>

#define L_LEN 4096
#define CIN   128
#define COUT  128
#define NB    32
#define KTOT  384            // 3 * CIN, kappa = k*128 + i
#define TN    64             // h-tile per block (halved: acc 32 AGPR, 4 blocks/CU)
#define ROWS  (TN + 2)       // 66 (halo of 1 on each side)

typedef __bf16 bf16x8 __attribute__((ext_vector_type(8)));
typedef float  f32x4  __attribute__((ext_vector_type(4)));

__device__ __forceinline__ uint16_t f2bf(float f) {
    union { float f; uint32_t u; } v; v.f = f;
    return (uint16_t)((v.u + 0x7fffu + ((v.u >> 16) & 1u)) >> 16);  // RNE
}
__device__ __forceinline__ uint32_t pack2(float lo, float hi) {
    return (uint32_t)f2bf(lo) | ((uint32_t)f2bf(hi) << 16);
}

// ---- Prologue: combined bf16 weights in MFMA-FRAGMENT order + cbias ----
// Wc2 index = (((b*4 + og)*12 + t)*2 + mt)*512 + lane*8 + j
//   o   = og*32 + mt*16 + (lane&15)
//   col = t*32 + (lane>>4)*8 + j        (col = k*128 + i)
// so geps_conv's af load is one contiguous 1 KiB per wave instruction.
__global__ __launch_bounds__(256) void geps_combine(
    const float* __restrict__ codes, const float* __restrict__ weight,
    const float* __restrict__ Amat,  const float* __restrict__ Bmat,
    const float* __restrict__ bias,  const float* __restrict__ bias_ctx,
    uint16_t* __restrict__ Wc, float* __restrict__ cbias)
{
    int tid = blockIdx.x * 256 + threadIdx.x;
    if (tid < NB * COUT * KTOT) {
        int j    = tid & 7;
        int lane = (tid >> 3) & 63;
        int mt   = (tid >> 9) & 1;
        int tmp  = tid >> 10;
        int t    = tmp % 12;
        int bo   = tmp / 12;          // b*4 + og
        int og   = bo & 3;
        int b    = bo >> 2;
        int col  = t * 32 + (lane >> 4) * 8 + j;   // kappa = k*128 + i
        int k    = col >> 7;
        int i    = col & 127;
        int o    = og * 32 + mt * 16 + (lane & 15);
        float cw = 0.f;
        #pragma unroll
        for (int c = 0; c < 2; ++c) {
            float a = Amat[i * 6 + c * 3 + k];
            #pragma unroll
            for (int r = 0; r < 2; ++r)
                cw += a * codes[b * 4 + c * 2 + r] * Bmat[o * 6 + r * 3 + k];
        }
        float val = weight[o * 384 + i * 3 + k] + cw;   // FACTOR = 1
        Wc[tid] = f2bf(val);
    }
    if (tid < NB * COUT) {
        int b = tid >> 7, o = tid & 127;
        float cb = bias[o];
        #pragma unroll
        for (int c = 0; c < 2; ++c)
            cb += codes[b * 4 + c * 2 + c] * bias_ctx[c * 128 + o];
        cbias[tid] = cb;
    }
}

// ---- Main: per-batch GEMM, M=o(128) x N=h(64/block) x K=384, bf16 MFMA ----
// 4 blocks/CU resident (acc 32 AGPR + ~70 arch <= 128): phase overlap across
// blocks keeps HBM busy. A-fragments streamed from L2 (coalesced fragment
// layout) with 1-iteration prefetch instead of a 96-reg preload.
__global__ __launch_bounds__(256, 4) void geps_conv(
    const float* __restrict__ in, const uint16_t* __restrict__ Wc,
    const float* __restrict__ cbias, float* __restrict__ out)
{
    // Xt: transposed input tile, element (r,i) at r*128 + (((i>>3)^(r&15))<<3) + (i&7)
    __shared__ uint16_t __attribute__((aligned(16))) Xt[ROWS * 128];
    __shared__ float cb[COUT];

    const int tid  = threadIdx.x;
    const int b    = blockIdx.y;
    const int h0   = blockIdx.x * TN;
    const int lane = tid & 63;
    const int wid  = tid >> 6;
    const int m16  = lane & 15;
    const int q    = lane >> 4;
    const int mq   = wid * 32;           // wave's o-offset (4 waves x 32 o)

    if (tid < COUT) cb[tid] = cbias[b * COUT + tid];

    const float* inb = in + (size_t)b * CIN * L_LEN;

    // A-fragment stream base for this (b, wave): 12 steps x 2 mt x 512 bf16
    const uint16_t* WcW = Wc + (size_t)(b * 4 + wid) * 12288 + lane * 8;
    // issue first A-fragment loads early: L2 latency hides under transpose
    bf16x8 ac0 = *(const bf16x8*)(WcW);
    bf16x8 ac1 = *(const bf16x8*)(WcW + 512);

    // --- core transpose: 32 i-quads x 16 h-quads, float4 loads, uint2 writes
    #pragma unroll
    for (int it = 0; it < 2; ++it) {
        int task = it * 256 + tid;       // 512 tasks
        int p4   = task >> 4;            // i-quad (i = 4p4 .. 4p4+3)
        int qd   = task & 15;            // h-quad
        const float* r0 = inb + (size_t)(4 * p4) * L_LEN + h0 + 4 * qd;
        float4 a0 = *(const float4*)(r0);
        float4 a1 = *(const float4*)(r0 + L_LEN);
        float4 a2 = *(const float4*)(r0 + 2 * L_LEN);
        float4 a3 = *(const float4*)(r0 + 3 * L_LEN);
        const int off = (4 * p4) & 7;    // 0 or 4
        const int pc  = p4 >> 1;         // i-chunk
        const float v0[4] = {a0.x, a0.y, a0.z, a0.w};
        const float v1[4] = {a1.x, a1.y, a1.z, a1.w};
        const float v2[4] = {a2.x, a2.y, a2.z, a2.w};
        const float v3[4] = {a3.x, a3.y, a3.z, a3.w};
        #pragma unroll
        for (int j = 0; j < 4; ++j) {
            int r  = 1 + 4 * qd + j;     // global h = h0 + 4qd + j
            int ch = pc ^ (r & 15);
            uint2 w;
            w.x = pack2(v0[j], v1[j]);
            w.y = pack2(v2[j], v3[j]);
            *(uint2*)&Xt[r * 128 + (ch << 3) + off] = w;
        }
    }
    // --- halo columns r=0 (h0-1) and r=65 (h0+64), circular ---
    if (tid < 128) {
        int p    = tid & 63;             // i-pair
        int side = tid >> 6;             // 0: left, 1: right
        int r    = side ? (ROWS - 1) : 0;
        int gh   = (h0 - 1 + r) & (L_LEN - 1);
        float x0 = inb[(size_t)(2 * p)     * L_LEN + gh];
        float x1 = inb[(size_t)(2 * p + 1) * L_LEN + gh];
        int chunk = (p >> 2) ^ (r & 15);
        *(uint32_t*)&Xt[r * 128 + (chunk << 3) + ((2 * p) & 7)] = pack2(x0, x1);
    }

    f32x4 acc[2][4];
    #pragma unroll
    for (int a = 0; a < 2; ++a)
        #pragma unroll
        for (int c = 0; c < 4; ++c) acc[a][c] = 0.0f;

    __syncthreads();                     // Xt + cb ready; only barrier

    #pragma unroll 1
    for (int t = 0; t < 12; ++t) {
        // prefetch next step's A-fragments (t=11 reloads itself; dead value)
        const uint16_t* pn = WcW + ((t + 1 < 12) ? (t + 1) : 11) * 1024;
        bf16x8 an0 = *(const bf16x8*)(pn);
        bf16x8 an1 = *(const bf16x8*)(pn + 512);

        const int k   = t >> 2;          // kernel tap of this K-step
        const int i0c = (t & 3) << 2;    // i-chunk base
        bf16x8 bf[4];
        #pragma unroll
        for (int nt = 0; nt < 4; ++nt) {
            int r  = nt * 16 + m16 + k;  // Xt row = h_local + k
            int ch = (i0c + q) ^ (r & 15);
            bf[nt] = *(const bf16x8*)&Xt[r * 128 + (ch << 3)];
        }
        #pragma unroll
        for (int nt = 0; nt < 4; ++nt) {
            acc[0][nt] = __builtin_amdgcn_mfma_f32_16x16x32_bf16(ac0, bf[nt], acc[0][nt], 0, 0, 0);
            acc[1][nt] = __builtin_amdgcn_mfma_f32_16x16x32_bf16(ac1, bf[nt], acc[1][nt], 0, 0, 0);
        }
        ac0 = an0; ac1 = an1;
    }

    // --- epilogue: C/D layout col=lane&15 (h), row=(lane>>4)*4+reg (o) ---
    float* outb = out + (size_t)b * COUT * L_LEN + h0;
    #pragma unroll
    for (int mt = 0; mt < 2; ++mt) {
        #pragma unroll
        for (int reg = 0; reg < 4; ++reg) {
            int o = mq + mt * 16 + q * 4 + reg;
            float bv = cb[o];
            float* orow = outb + (size_t)o * L_LEN;
            #pragma unroll
            for (int nt = 0; nt < 4; ++nt)
                __builtin_nontemporal_store(acc[mt][nt][reg] + bv,
                                            &orow[nt * 16 + m16]);
        }
    }
}

extern "C" void kernel_launch(void* const* d_in, const int* in_sizes, int n_in,
                              void* d_out, int out_size, void* d_ws, size_t ws_size,
                              hipStream_t stream) {
    const float* input    = (const float*)d_in[0];
    const float* codes    = (const float*)d_in[1];
    const float* weight   = (const float*)d_in[2];
    const float* Amat     = (const float*)d_in[3];
    const float* Bmat     = (const float*)d_in[4];
    const float* bias     = (const float*)d_in[5];
    const float* bias_ctx = (const float*)d_in[6];
    float* out = (float*)d_out;

    uint16_t* Wc    = (uint16_t*)d_ws;
    float*    cbias = (float*)((char*)d_ws + (size_t)NB * COUT * KTOT * 2);

    geps_combine<<<dim3((NB * COUT * KTOT) / 256), 256, 0, stream>>>(
        codes, weight, Amat, Bmat, bias, bias_ctx, Wc, cbias);
    geps_conv<<<dim3(L_LEN / TN, NB), 256, 0, stream>>>(input, Wc, cbias, out);
}